// Round 10
// baseline (976.157 us; speedup 1.0000x reference)
//
#include <hip/hip_runtime.h>
#include <math.h>

#define BB 512   // batch
#define TT 256   // time steps
#define EE 128   // hidden
#define GG 512   // 4*E gate rows
#define XROW 257 // T+1
#define NCHUNK 5 // decoder chunks per id

typedef __attribute__((ext_vector_type(8))) short bf16x8;
typedef __attribute__((ext_vector_type(4))) float f32x4;

__device__ __forceinline__ float sig_(float v){ return 1.0f/(1.0f+__expf(-v)); }
__device__ __forceinline__ float tanh2_(float v){ return fmaf(2.0f, sig_(2.0f*v), -1.0f); }
__device__ __forceinline__ unsigned short bf16_(float f){  // RNE f32->bf16
    unsigned u = __float_as_uint(f);
    return (unsigned short)((u + 0x7fffu + ((u>>16)&1u)) >> 16);
}
// Permuted tile rows: wave w owns e-chunk [8w,8w+8). Tile P=0 packs i|f rows,
// P=1 packs g|o rows: rho<8 -> first gate row 8w+rho; rho>=8 -> second gate
// row 128 + 8w + (rho-8). So C rows 4q+i give lane q<2 the (i,g) values and
// lane q>=2 the (f,o) values FOR THE SAME e -> swap via shfl_xor(.,32).
__device__ __forceinline__ int perm_row(int P, int w, int rho){
    return (P ? 256 : 0) + ((rho < 8) ? (8*w + rho) : (120 + 8*w + rho));
}
__device__ __forceinline__ bf16x8 load_afrag(const float* W, int row, int k0){
    const float4* p = (const float4*)(W + row*EE + k0);
    float4 a = p[0], b = p[1];
    bf16x8 r;
    r[0]=(short)bf16_(a.x); r[1]=(short)bf16_(a.y); r[2]=(short)bf16_(a.z); r[3]=(short)bf16_(a.w);
    r[4]=(short)bf16_(b.x); r[5]=(short)bf16_(b.y); r[6]=(short)bf16_(b.z); r[7]=(short)bf16_(b.w);
    return r;
}

template <int IS_DEC>
__global__ __attribute__((amdgpu_flat_work_group_size(1024,1024)))
void lstm_k(const float* __restrict__ x,
            const float* __restrict__ Wg_all,
            const float* __restrict__ wi_all,
            const float* __restrict__ b_all,
            const float* __restrict__ lw_all,
            const float* __restrict__ lb_all,
            float* __restrict__ ws_h,
            float* __restrict__ ws_c,
            float* __restrict__ out)
{
    const int t    = threadIdx.x;   // 1024 threads = 16 waves
    const int w    = t >> 6;        // wave owns e-chunk 8w..8w+7
    const int lane = t & 63;
    const int q    = lane >> 4;
    const int c    = lane & 15;     // batch column

    __shared__ unsigned short h_lds[2][16*EE];  // double-buffered bf16 h, swizzled
    __shared__ float bw_lds[2][256][2];         // permuted (bias, wi) per row
    __shared__ float x_lds[TT*16];              // inputs [step][col]
    __shared__ float psum_lds[2][256];          // [buf][w*16+c]
    __shared__ float u0_lds[16];
    __shared__ float out_lds[16][TT+1];         // padded rows
    __shared__ int   id_lds[BB];
    __shared__ int   blist[16];
    __shared__ int   nslots_s;
    __shared__ float bl_sh;

    int myid = 0, nslots = 16;
    if (IS_DEC){
        myid = blockIdx.x / NCHUNK;
        int chunk = blockIdx.x % NCHUNK;
        for (int j = t; j < BB; j += 1024) id_lds[j] = (int)x[j*XROW + TT];
        if (t < 16) blist[t] = 0;
        __syncthreads();
        if (t < BB && id_lds[t] == myid){
            int r = 0;
            for (int j = 0; j < t; ++j) r += (id_lds[j] == myid) ? 1 : 0;
            int slot = r - chunk*16;
            if (slot >= 0 && slot < 16) blist[slot] = t;
        }
        if (t == 0){
            int cnt = 0;
            for (int j = 0; j < BB; ++j) cnt += (id_lds[j] == myid) ? 1 : 0;
            int ns = cnt - chunk*16;
            nslots_s = ns < 0 ? 0 : (ns > 16 ? 16 : ns);
            bl_sh = lb_all[myid];
        }
        __syncthreads();
        nslots = nslots_s;
        if (nslots == 0) return;    // uniform exit before any loop barrier
    }
    const int gb = IS_DEC ? blist[c] : (blockIdx.x*16 + c);

    for (int j = t; j < TT*16; j += 1024){
        int s = j >> 4, cc = j & 15;
        int gbl = IS_DEC ? blist[cc] : (blockIdx.x*16 + cc);
        x_lds[j] = x[gbl*XROW + s];
    }

    const float* Wb  = Wg_all + (IS_DEC ? myid*GG*EE : 0);
    const float* wib = wi_all + (IS_DEC ? myid*GG : 0);
    const float* bbb = b_all  + (IS_DEC ? myid*GG : 0);

    // permuted f32 (bias, wi) tables
    for (int j = t; j < 512; j += 1024){
        int P = j >> 8, idx = j & 255;
        int row = perm_row(P, idx >> 4, idx & 15);
        bw_lds[P][idx][0] = bbb[row];
        bw_lds[P][idx][1] = wib[row];
    }

    // weights: 8 A-frags = 32 VGPR (bf16)
    bf16x8 wa0_0, wa0_1, wa0_2, wa0_3, wa1_0, wa1_1, wa1_2, wa1_3;
    {
        int rho = lane & 15, kb = 8*(lane>>4);
        int r0 = perm_row(0, w, rho), r1 = perm_row(1, w, rho);
        wa0_0 = load_afrag(Wb, r0, kb);      wa1_0 = load_afrag(Wb, r1, kb);
        wa0_1 = load_afrag(Wb, r0, 32+kb);   wa1_1 = load_afrag(Wb, r1, 32+kb);
        wa0_2 = load_afrag(Wb, r0, 64+kb);   wa1_2 = load_afrag(Wb, r1, 64+kb);
        wa0_3 = load_afrag(Wb, r0, 96+kb);   wa1_3 = load_afrag(Wb, r1, 96+kb);
    }

    const int e0 = 8*w + 4*q;       // meaningful for q<2 (state owner)
    float c0=0.f, c1=0.f, c2=0.f, c3=0.f;
    float4 wl4 = make_float4(0.f,0.f,0.f,0.f);

    if (!IS_DEC){
        ((unsigned*)&h_lds[0][0])[t] = 0u;   // zero h buf0 (1024 uints = 4 KB)
    } else if (q < 2){
        float4 hv = *(const float4*)&ws_h[gb*EE + e0];
        float4 cv = *(const float4*)&ws_c[gb*EE + e0];
        c0=cv.x; c1=cv.y; c2=cv.z; c3=cv.w;
        wl4 = *(const float4*)&lw_all[myid*EE + e0];
        unsigned lo = (unsigned)bf16_(hv.x) | ((unsigned)bf16_(hv.y) << 16);
        unsigned hi = (unsigned)bf16_(hv.z) | ((unsigned)bf16_(hv.w) << 16);
        *(uint2*)&h_lds[0][c*EE + ((w ^ c) << 3) + 4*q] = make_uint2(lo, hi);
        float p = hv.x*wl4.x + hv.y*wl4.y + hv.z*wl4.z + hv.w*wl4.w;
        p += __shfl_xor(p, 16);
        if (q == 0) psum_lds[0][w*16 + c] = p;
    }
    __syncthreads();
    if (IS_DEC && t < 16){
        float s16 = 0.f;
        #pragma unroll
        for (int j = 0; j < 16; ++j) s16 += psum_lds[0][j*16 + t];
        u0_lds[t] = s16 + bl_sh;
    }
    __syncthreads();

    for (int s = 0; s < TT; ++s){
        const int cur = s & 1;
        // previous step's output reduction: idle q2 lanes of wave 0
        if (IS_DEC && w == 0 && q == 2 && s > 0){
            float s16 = 0.f;
            #pragma unroll
            for (int j = 0; j < 16; ++j) s16 += psum_lds[cur ^ 1][j*16 + c];
            out_lds[c][TT - s] = s16 + bl_sh;
        }

        float u;
        if (IS_DEC) u = (s == 0) ? u0_lds[c] : x_lds[(TT - s)*16 + c];
        else        u = x_lds[s*16 + c];

        f32x4 acc0 = {0,0,0,0}, acc1 = {0,0,0,0};
        {
            const unsigned short* hb = &h_lds[cur][c*EE];
            bf16x8 bf0 = *(const bf16x8*)&hb[(((0 + q) ^ c) << 3)];
            bf16x8 bf1 = *(const bf16x8*)&hb[(((4 + q) ^ c) << 3)];
            bf16x8 bf2 = *(const bf16x8*)&hb[(((8 + q) ^ c) << 3)];
            bf16x8 bf3 = *(const bf16x8*)&hb[(((12 + q) ^ c) << 3)];
            acc0 = __builtin_amdgcn_mfma_f32_16x16x32_bf16(wa0_0, bf0, acc0, 0,0,0);
            acc1 = __builtin_amdgcn_mfma_f32_16x16x32_bf16(wa1_0, bf0, acc1, 0,0,0);
            acc0 = __builtin_amdgcn_mfma_f32_16x16x32_bf16(wa0_1, bf1, acc0, 0,0,0);
            acc1 = __builtin_amdgcn_mfma_f32_16x16x32_bf16(wa1_1, bf1, acc1, 0,0,0);
            acc0 = __builtin_amdgcn_mfma_f32_16x16x32_bf16(wa0_2, bf2, acc0, 0,0,0);
            acc1 = __builtin_amdgcn_mfma_f32_16x16x32_bf16(wa1_2, bf2, acc1, 0,0,0);
            acc0 = __builtin_amdgcn_mfma_f32_16x16x32_bf16(wa0_3, bf3, acc0, 0,0,0);
            acc1 = __builtin_amdgcn_mfma_f32_16x16x32_bf16(wa1_3, bf3, acc1, 0,0,0);
        }

        const float4* bp1 = (const float4*)&bw_lds[0][w*16 + 4*q][0];
        const float4* bp2 = (const float4*)&bw_lds[1][w*16 + 4*q][0];
        float4 b1a = bp1[0], b1b = bp1[1], b2a = bp2[0], b2b = bp2[1];

        // P1: sigmoid for all (i if q<2, f if q>=2)
        float g10 = sig_(acc0[0] + fmaf(u, b1a.y, b1a.x));
        float g11 = sig_(acc0[1] + fmaf(u, b1a.w, b1a.z));
        float g12 = sig_(acc0[2] + fmaf(u, b1b.y, b1b.x));
        float g13 = sig_(acc0[3] + fmaf(u, b1b.w, b1b.z));
        // P2: tanh (g) if q<2, sigmoid (o) if q>=2 -- branch-free
        const float sc = (q < 2) ? 2.0f : 1.0f;
        const float co = (q < 2) ? -1.0f : 0.0f;
        float g20 = fmaf(sc, sig_(sc*(acc1[0] + fmaf(u, b2a.y, b2a.x))), co);
        float g21 = fmaf(sc, sig_(sc*(acc1[1] + fmaf(u, b2a.w, b2a.z))), co);
        float g22 = fmaf(sc, sig_(sc*(acc1[2] + fmaf(u, b2b.y, b2b.x))), co);
        float g23 = fmaf(sc, sig_(sc*(acc1[3] + fmaf(u, b2b.w, b2b.z))), co);

        // in-wave gate swap: q<2 receives f (P1) and o (P2) from lane^32
        float f0 = __shfl_xor(g10, 32), f1 = __shfl_xor(g11, 32);
        float f2 = __shfl_xor(g12, 32), f3 = __shfl_xor(g13, 32);
        float o0 = __shfl_xor(g20, 32), o1 = __shfl_xor(g21, 32);
        float o2 = __shfl_xor(g22, 32), o3 = __shfl_xor(g23, 32);

        if (q < 2){
            c0 = fmaf(f0, c0, g10*g20);
            c1 = fmaf(f1, c1, g11*g21);
            c2 = fmaf(f2, c2, g12*g22);
            c3 = fmaf(f3, c3, g13*g23);
            float h0 = o0 * tanh2_(c0);
            float h1 = o1 * tanh2_(c1);
            float h2 = o2 * tanh2_(c2);
            float h3 = o3 * tanh2_(c3);
            unsigned lo = (unsigned)bf16_(h0) | ((unsigned)bf16_(h1) << 16);
            unsigned hi = (unsigned)bf16_(h2) | ((unsigned)bf16_(h3) << 16);
            *(uint2*)&h_lds[cur ^ 1][c*EE + ((w ^ c) << 3) + 4*q] = make_uint2(lo, hi);
            if (IS_DEC){
                float p = h0*wl4.x + h1*wl4.y + h2*wl4.z + h3*wl4.w;
                p += __shfl_xor(p, 16);
                if (q == 0) psum_lds[cur][w*16 + c] = p;
            }
            if (!IS_DEC && s == TT-1){
                *(float4*)&ws_h[gb*EE + e0] = make_float4(h0,h1,h2,h3);
                *(float4*)&ws_c[gb*EE + e0] = make_float4(c0,c1,c2,c3);
            }
        }
        __syncthreads();
    }

    if (IS_DEC){
        if (w == 0 && q == 2){   // flush last step (s=TT-1 -> position 0)
            float s16 = 0.f;
            #pragma unroll
            for (int j = 0; j < 16; ++j) s16 += psum_lds[(TT-1)&1][j*16 + c];
            out_lds[c][0] = s16 + bl_sh;
        }
        __syncthreads();
        for (int j = t; j < 16*TT; j += 1024){
            int sl = j >> 8, pos = j & 255;
            if (sl < nslots) out[blist[sl]*TT + pos] = out_lds[sl][pos];
        }
    }
}

extern "C" void kernel_launch(void* const* d_in, const int* in_sizes, int n_in,
                              void* d_out, int out_size, void* d_ws, size_t ws_size,
                              hipStream_t stream) {
    const float* x       = (const float*)d_in[0];
    const float* enc_wih = (const float*)d_in[1];
    const float* enc_whh = (const float*)d_in[2];
    const float* enc_b   = (const float*)d_in[3];
    const float* dec_wih = (const float*)d_in[4];
    const float* dec_whh = (const float*)d_in[5];
    const float* dec_b   = (const float*)d_in[6];
    const float* lin_w   = (const float*)d_in[7];
    const float* lin_b   = (const float*)d_in[8];
    float* out  = (float*)d_out;
    float* wsf  = (float*)d_ws;
    float* ws_h = wsf;
    float* ws_c = wsf + BB*EE;   // 512 KB total

    hipLaunchKernelGGL((lstm_k<0>), dim3(BB/16), dim3(1024), 0, stream,
                       x, enc_whh, enc_wih, enc_b, lin_w, lin_b, ws_h, ws_c, out);
    hipLaunchKernelGGL((lstm_k<1>), dim3(16*NCHUNK), dim3(1024), 0, stream,
                       x, dec_whh, dec_wih, dec_b, lin_w, lin_b, ws_h, ws_c, out);
}

// Round 11
// 800.551 us; speedup vs baseline: 1.2194x; 1.2194x over previous
//
#include <hip/hip_runtime.h>
#include <math.h>

#define BB 512   // batch
#define TT 256   // time steps
#define EE 128   // hidden
#define GG 512   // 4*E gate rows
#define XROW 257 // T+1
#define NCHUNK 5 // decoder chunks per id

typedef __attribute__((ext_vector_type(8))) short bf16x8;
typedef __attribute__((ext_vector_type(4))) float f32x4;

__device__ __forceinline__ float sig_(float v){ return 1.0f/(1.0f+__expf(-v)); }
__device__ __forceinline__ float tanh2_(float v){ return fmaf(2.0f, sig_(2.0f*v), -1.0f); }
__device__ __forceinline__ unsigned short bf16_(float f){  // RNE f32->bf16
    unsigned u = __float_as_uint(f);
    return (unsigned short)((u + 0x7fffu + ((u>>16)&1u)) >> 16);
}
__device__ __forceinline__ float blo_(unsigned p){ return __uint_as_float(p << 16); }
__device__ __forceinline__ float bhi_(unsigned p){ return __uint_as_float(p & 0xffff0000u); }

// Gate-interleaved permutation: tile P of wave w, tile-row rho in [0,16):
// source gate row = (rho&3)*128 + 8w + 4P + (rho>>2).
// => C/D lane (q,c), reg r holds gate r of element e = 8w + 4P + q, col c.
__device__ __forceinline__ int perm_row(int P, int w, int rho){
    return (rho & 3)*EE + 8*w + 4*P + (rho >> 2);
}
__device__ __forceinline__ bf16x8 load_afrag(const float* W, int row, int k0){
    const float4* p = (const float4*)(W + row*EE + k0);
    float4 a = p[0], b = p[1];
    bf16x8 r;
    r[0]=(short)bf16_(a.x); r[1]=(short)bf16_(a.y); r[2]=(short)bf16_(a.z); r[3]=(short)bf16_(a.w);
    r[4]=(short)bf16_(b.x); r[5]=(short)bf16_(b.y); r[6]=(short)bf16_(b.z); r[7]=(short)bf16_(b.w);
    return r;
}

template <int IS_DEC>
__global__ __attribute__((amdgpu_flat_work_group_size(1024,1024)))
void lstm_k(const float* __restrict__ x,
            const float* __restrict__ Wg_all,
            const float* __restrict__ wi_all,
            const float* __restrict__ b_all,
            const float* __restrict__ lw_all,
            const float* __restrict__ lb_all,
            float* __restrict__ ws_h,
            float* __restrict__ ws_c,
            float* __restrict__ out)
{
    const int t    = threadIdx.x;   // 1024 threads = 16 waves
    const int w    = t >> 6;        // wave owns e-chunk 8w..8w+7
    const int lane = t & 63;
    const int q    = lane >> 4;
    const int c    = lane & 15;     // batch column

    __shared__ unsigned short h_lds[2][16*EE];  // double-buffered bf16 h, swizzled
    __shared__ unsigned bwp_lds[512];           // packed (wi<<16|bias) bf16 pairs
    __shared__ float x_lds[TT*16];              // inputs [step][col]
    __shared__ float psum_lds[2][256];          // [buf][w*16+c]
    __shared__ float u0_lds[16];
    __shared__ float out_lds[16][TT+1];
    __shared__ int   id_lds[BB];
    __shared__ int   blist[16];
    __shared__ int   nslots_s;
    __shared__ float bl_sh;

    int myid = 0, nslots = 16;
    if (IS_DEC){
        myid = blockIdx.x / NCHUNK;
        int chunk = blockIdx.x % NCHUNK;
        for (int j = t; j < BB; j += 1024) id_lds[j] = (int)x[j*XROW + TT];
        if (t < 16) blist[t] = 0;
        __syncthreads();
        if (t < BB && id_lds[t] == myid){
            int r = 0;
            for (int j = 0; j < t; ++j) r += (id_lds[j] == myid) ? 1 : 0;
            int slot = r - chunk*16;
            if (slot >= 0 && slot < 16) blist[slot] = t;
        }
        if (t == 0){
            int cnt = 0;
            for (int j = 0; j < BB; ++j) cnt += (id_lds[j] == myid) ? 1 : 0;
            int ns = cnt - chunk*16;
            nslots_s = ns < 0 ? 0 : (ns > 16 ? 16 : ns);
            bl_sh = lb_all[myid];
        }
        __syncthreads();
        nslots = nslots_s;
        if (nslots == 0) return;    // uniform exit before loop barriers
    }
    const int gb = IS_DEC ? blist[c] : (blockIdx.x*16 + c);

    for (int j = t; j < TT*16; j += 1024){
        int s = j >> 4, cc = j & 15;
        int gbl = IS_DEC ? blist[cc] : (blockIdx.x*16 + cc);
        x_lds[j] = x[gbl*XROW + s];
    }

    const float* Wb  = Wg_all + (IS_DEC ? myid*GG*EE : 0);
    const float* wib = wi_all + (IS_DEC ? myid*GG : 0);
    const float* bbb = b_all  + (IS_DEC ? myid*GG : 0);

    // packed (wi, bias) table: index (w*4+q)*8 + P*4 + r
    for (int j = t; j < 512; j += 1024){
        int w_ = j >> 5, rem = j & 31, q_ = rem >> 3, k = rem & 7;
        int row = (k & 3)*EE + 8*w_ + 4*(k >> 2) + q_;
        bwp_lds[j] = ((unsigned)bf16_(wib[row]) << 16) | (unsigned)bf16_(bbb[row]);
    }

    // weights: 8 A-frags = 32 VGPR (bf16), gate-interleaved rows
    bf16x8 a00, a01, a02, a03, a10, a11, a12, a13;
    {
        int rho = lane & 15, kb = 8*(lane>>4);
        int r0 = perm_row(0, w, rho), r1 = perm_row(1, w, rho);
        a00 = load_afrag(Wb, r0, kb);      a10 = load_afrag(Wb, r1, kb);
        a01 = load_afrag(Wb, r0, 32+kb);   a11 = load_afrag(Wb, r1, 32+kb);
        a02 = load_afrag(Wb, r0, 64+kb);   a12 = load_afrag(Wb, r1, 64+kb);
        a03 = load_afrag(Wb, r0, 96+kb);   a13 = load_afrag(Wb, r1, 96+kb);
    }

    const int e0 = 8*w + q;         // this lane's two elements
    const int e1 = 8*w + 4 + q;
    float cst0 = 0.f, cst1 = 0.f;
    float wl0 = 0.f, wl1 = 0.f;

    if (!IS_DEC){
        ((unsigned*)&h_lds[0][0])[t] = 0u;   // 1024 uints = whole buf0
    } else {
        float h0 = ws_h[gb*EE + e0];
        float h1 = ws_h[gb*EE + e1];
        cst0 = ws_c[gb*EE + e0];
        cst1 = ws_c[gb*EE + e1];
        wl0 = lw_all[myid*EE + e0];
        wl1 = lw_all[myid*EE + e1];
        unsigned short* hbw = &h_lds[0][c*EE + ((w ^ c) << 3)];
        hbw[q]     = bf16_(h0);
        hbw[q + 4] = bf16_(h1);
        float p = h0*wl0 + h1*wl1;
        p += __shfl_xor(p, 16);
        p += __shfl_xor(p, 32);
        if (q == 0) psum_lds[0][w*16 + c] = p;
    }
    __syncthreads();
    if (IS_DEC && t < 16){
        float s16 = 0.f;
        #pragma unroll
        for (int j = 0; j < 16; ++j) s16 += psum_lds[0][j*16 + t];
        u0_lds[t] = s16 + bl_sh;
    }
    __syncthreads();

    // hoist packed bias/wi into 8 registers (step-invariant)
    const uint4* bq = (const uint4*)&bwp_lds[(w*4 + q)*8];
    const uint4 bwa = bq[0];   // P=0: rows i,f,g,o of e0
    const uint4 bwb = bq[1];   // P=1: rows i,f,g,o of e1

    for (int s = 0; s < TT; ++s){
        const int cur = s & 1;
        // rotated output flush of previous step (dec): one wave per step
        if (IS_DEC && s > 0 && w == (s & 15) && lane < 16){
            float s16 = 0.f;
            #pragma unroll
            for (int j = 0; j < 16; ++j) s16 += psum_lds[cur ^ 1][j*16 + lane];
            out_lds[lane][TT - s] = s16 + bl_sh;
        }

        float u;
        if (IS_DEC) u = (s == 0) ? u0_lds[c] : x_lds[(TT - s)*16 + c];
        else        u = x_lds[s*16 + c];

        f32x4 acc0 = {0,0,0,0}, acc1 = {0,0,0,0};
        const unsigned short* hb = &h_lds[cur][c*EE];
        {
            bf16x8 bf0 = *(const bf16x8*)&hb[(((0 + q) ^ c) << 3)];
            acc0 = __builtin_amdgcn_mfma_f32_16x16x32_bf16(a00, bf0, acc0, 0,0,0);
            acc1 = __builtin_amdgcn_mfma_f32_16x16x32_bf16(a10, bf0, acc1, 0,0,0);
            bf16x8 bf1 = *(const bf16x8*)&hb[(((4 + q) ^ c) << 3)];
            acc0 = __builtin_amdgcn_mfma_f32_16x16x32_bf16(a01, bf1, acc0, 0,0,0);
            acc1 = __builtin_amdgcn_mfma_f32_16x16x32_bf16(a11, bf1, acc1, 0,0,0);
            bf16x8 bf2 = *(const bf16x8*)&hb[(((8 + q) ^ c) << 3)];
            acc0 = __builtin_amdgcn_mfma_f32_16x16x32_bf16(a02, bf2, acc0, 0,0,0);
            acc1 = __builtin_amdgcn_mfma_f32_16x16x32_bf16(a12, bf2, acc1, 0,0,0);
            bf16x8 bf3 = *(const bf16x8*)&hb[(((12 + q) ^ c) << 3)];
            acc0 = __builtin_amdgcn_mfma_f32_16x16x32_bf16(a03, bf3, acc0, 0,0,0);
            acc1 = __builtin_amdgcn_mfma_f32_16x16x32_bf16(a13, bf3, acc1, 0,0,0);
        }

        // element e0 (P=0): all four gates lane-local
        float i0 = sig_  (acc0[0] + fmaf(u, bhi_(bwa.x), blo_(bwa.x)));
        float f0 = sig_  (acc0[1] + fmaf(u, bhi_(bwa.y), blo_(bwa.y)));
        float g0 = tanh2_(acc0[2] + fmaf(u, bhi_(bwa.z), blo_(bwa.z)));
        float o0 = sig_  (acc0[3] + fmaf(u, bhi_(bwa.w), blo_(bwa.w)));
        cst0 = fmaf(f0, cst0, i0*g0);
        float h0 = o0 * tanh2_(cst0);
        // element e1 (P=1)
        float i1 = sig_  (acc1[0] + fmaf(u, bhi_(bwb.x), blo_(bwb.x)));
        float f1 = sig_  (acc1[1] + fmaf(u, bhi_(bwb.y), blo_(bwb.y)));
        float g1 = tanh2_(acc1[2] + fmaf(u, bhi_(bwb.z), blo_(bwb.z)));
        float o1 = sig_  (acc1[3] + fmaf(u, bhi_(bwb.w), blo_(bwb.w)));
        cst1 = fmaf(f1, cst1, i1*g1);
        float h1 = o1 * tanh2_(cst1);

        // h write (both elements in chunk w: offsets q and q+4)
        unsigned short* hbw = &h_lds[cur ^ 1][c*EE + ((w ^ c) << 3)];
        hbw[q]     = bf16_(h0);
        hbw[q + 4] = bf16_(h1);

        if (IS_DEC){
            float p = h0*wl0 + h1*wl1;
            p += __shfl_xor(p, 16);
            p += __shfl_xor(p, 32);
            if (q == 0) psum_lds[cur][w*16 + c] = p;
        }
        if (!IS_DEC && s == TT-1){
            ws_h[gb*EE + e0] = h0;
            ws_h[gb*EE + e1] = h1;
            ws_c[gb*EE + e0] = cst0;
            ws_c[gb*EE + e1] = cst1;
        }
        __syncthreads();
    }

    if (IS_DEC){
        if (w == 0 && lane < 16){   // flush last step (s=TT-1 -> position 0)
            float s16 = 0.f;
            #pragma unroll
            for (int j = 0; j < 16; ++j) s16 += psum_lds[(TT-1)&1][j*16 + lane];
            out_lds[lane][0] = s16 + bl_sh;
        }
        __syncthreads();
        for (int j = t; j < 16*TT; j += 1024){
            int sl = j >> 8, pos = j & 255;
            if (sl < nslots) out[blist[sl]*TT + pos] = out_lds[sl][pos];
        }
    }
}

extern "C" void kernel_launch(void* const* d_in, const int* in_sizes, int n_in,
                              void* d_out, int out_size, void* d_ws, size_t ws_size,
                              hipStream_t stream) {
    const float* x       = (const float*)d_in[0];
    const float* enc_wih = (const float*)d_in[1];
    const float* enc_whh = (const float*)d_in[2];
    const float* enc_b   = (const float*)d_in[3];
    const float* dec_wih = (const float*)d_in[4];
    const float* dec_whh = (const float*)d_in[5];
    const float* dec_b   = (const float*)d_in[6];
    const float* lin_w   = (const float*)d_in[7];
    const float* lin_b   = (const float*)d_in[8];
    float* out  = (float*)d_out;
    float* wsf  = (float*)d_ws;
    float* ws_h = wsf;
    float* ws_c = wsf + BB*EE;   // 512 KB total

    hipLaunchKernelGGL((lstm_k<0>), dim3(BB/16), dim3(1024), 0, stream,
                       x, enc_whh, enc_wih, enc_b, lin_w, lin_b, ws_h, ws_c, out);
    hipLaunchKernelGGL((lstm_k<1>), dim3(16*NCHUNK), dim3(1024), 0, stream,
                       x, dec_whh, dec_wih, dec_b, lin_w, lin_b, ws_h, ws_c, out);
}

// Round 12
// 790.713 us; speedup vs baseline: 1.2345x; 1.0124x over previous
//
#include <hip/hip_runtime.h>
#include <math.h>

#define BB 512   // batch
#define TT 256   // time steps
#define EE 128   // hidden
#define GG 512   // 4*E gate rows
#define XROW 257 // T+1
#define NCHUNK 5 // decoder chunks per id

typedef __attribute__((ext_vector_type(8))) short bf16x8;
typedef __attribute__((ext_vector_type(4))) float f32x4;

__device__ __forceinline__ float sig_(float v){ return 1.0f/(1.0f+__expf(-v)); }
__device__ __forceinline__ float tanh2_(float v){ return fmaf(2.0f, sig_(2.0f*v), -1.0f); }
__device__ __forceinline__ unsigned short bf16_(float f){  // RNE f32->bf16
    unsigned u = __float_as_uint(f);
    return (unsigned short)((u + 0x7fffu + ((u>>16)&1u)) >> 16);
}

// Adjacent-element gate-interleaved permutation: tile P of wave w, tile-row
// rho in [0,16): source gate row = (rho&3)*128 + 8w + 2*(rho>>2) + P.
// => C/D lane (q,c): acc_P regs 0..3 = gates (i,f,g,o) of element 8w+2q+P.
__device__ __forceinline__ int perm_row(int P, int w, int rho){
    return (rho & 3)*EE + 8*w + 2*(rho >> 2) + P;
}
__device__ __forceinline__ bf16x8 load_afrag(const float* W, int row, int k0){
    const float4* p = (const float4*)(W + row*EE + k0);
    float4 a = p[0], b = p[1];
    bf16x8 r;
    r[0]=(short)bf16_(a.x); r[1]=(short)bf16_(a.y); r[2]=(short)bf16_(a.z); r[3]=(short)bf16_(a.w);
    r[4]=(short)bf16_(b.x); r[5]=(short)bf16_(b.y); r[6]=(short)bf16_(b.z); r[7]=(short)bf16_(b.w);
    return r;
}

template <int IS_DEC>
__global__ __attribute__((amdgpu_flat_work_group_size(1024,1024)))
void lstm_k(const float* __restrict__ x,
            const float* __restrict__ Wg_all,
            const float* __restrict__ wi_all,
            const float* __restrict__ b_all,
            const float* __restrict__ lw_all,
            const float* __restrict__ lb_all,
            float* __restrict__ ws_h,
            float* __restrict__ ws_c,
            float* __restrict__ out)
{
    const int t    = threadIdx.x;   // 1024 threads = 16 waves
    const int w    = t >> 6;        // wave owns e-chunk 8w..8w+7
    const int lane = t & 63;
    const int q    = lane >> 4;
    const int c    = lane & 15;     // batch column (B-frag) / tile-row (A-frag)

    __shared__ unsigned short h_lds[2][16*EE];  // double-buffered bf16 h, swizzled
    __shared__ float x_lds[TT*16];              // inputs [step][col]
    __shared__ float psum_lds[2][512];          // [buf][(2w+qh)*16+c]
    __shared__ float u0_lds[16];
    __shared__ float out_lds[16][TT+1];
    __shared__ int   id_lds[BB];
    __shared__ int   blist[16];
    __shared__ int   nslots_s;
    __shared__ float bl_sh;

    int myid = 0, nslots = 16;
    if (IS_DEC){
        myid = blockIdx.x / NCHUNK;
        int chunk = blockIdx.x % NCHUNK;
        for (int j = t; j < BB; j += 1024) id_lds[j] = (int)x[j*XROW + TT];
        if (t < 16) blist[t] = 0;
        __syncthreads();
        if (t < BB && id_lds[t] == myid){
            int r = 0;
            for (int j = 0; j < t; ++j) r += (id_lds[j] == myid) ? 1 : 0;
            int slot = r - chunk*16;
            if (slot >= 0 && slot < 16) blist[slot] = t;
        }
        if (t == 0){
            int cnt = 0;
            for (int j = 0; j < BB; ++j) cnt += (id_lds[j] == myid) ? 1 : 0;
            int ns = cnt - chunk*16;
            nslots_s = ns < 0 ? 0 : (ns > 16 ? 16 : ns);
            bl_sh = lb_all[myid];
        }
        __syncthreads();
        nslots = nslots_s;
        if (nslots == 0) return;    // uniform exit before loop barriers
    }
    const int gb = IS_DEC ? blist[c] : (blockIdx.x*16 + c);

    for (int j = t; j < TT*16; j += 1024){
        int s = j >> 4, cc = j & 15;
        int gbl = IS_DEC ? blist[cc] : (blockIdx.x*16 + cc);
        x_lds[j] = x[gbl*XROW + s];
    }

    const float* Wb  = Wg_all + (IS_DEC ? myid*GG*EE : 0);
    const float* wib = wi_all + (IS_DEC ? myid*GG : 0);
    const float* bbb = b_all  + (IS_DEC ? myid*GG : 0);

    // weights: 8 main A-frags (32 VGPR) + 2 K-ext frags (8 VGPR)
    bf16x8 a00, a01, a02, a03, a10, a11, a12, a13;
    bf16x8 a40 = {0,0,0,0,0,0,0,0}, a41 = {0,0,0,0,0,0,0,0};
    {
        int kb = 8*q;
        int r0 = perm_row(0, w, c), r1 = perm_row(1, w, c);
        a00 = load_afrag(Wb, r0, kb);      a10 = load_afrag(Wb, r1, kb);
        a01 = load_afrag(Wb, r0, 32+kb);   a11 = load_afrag(Wb, r1, 32+kb);
        a02 = load_afrag(Wb, r0, 64+kb);   a12 = load_afrag(Wb, r1, 64+kb);
        a03 = load_afrag(Wb, r0, 96+kb);   a13 = load_afrag(Wb, r1, 96+kb);
        if (q == 0){   // K-ext tile: k=0 -> bias, k=1 -> wi
            a40[0] = (short)bf16_(bbb[r0]); a40[1] = (short)bf16_(wib[r0]);
            a41[0] = (short)bf16_(bbb[r1]); a41[1] = (short)bf16_(wib[r1]);
        }
    }

    const int e0 = 8*w + 2*q;       // lane's two adjacent elements e0, e0+1
    float cst0 = 0.f, cst1 = 0.f;
    float wl0 = 0.f, wl1 = 0.f;

    if (!IS_DEC){
        ((unsigned*)&h_lds[0][0])[t] = 0u;   // zero buf0
    } else {
        float2 hv = *(const float2*)&ws_h[gb*EE + e0];
        float2 cv = *(const float2*)&ws_c[gb*EE + e0];
        cst0 = cv.x; cst1 = cv.y;
        float2 wv = *(const float2*)&lw_all[myid*EE + e0];
        wl0 = wv.x; wl1 = wv.y;
        unsigned hp;
        asm("v_cvt_pk_bf16_f32 %0, %1, %2" : "=v"(hp) : "v"(hv.x), "v"(hv.y));
        *(unsigned*)&h_lds[0][c*EE + ((w ^ c) << 3) + 2*q] = hp;
        float p = hv.x*wl0 + hv.y*wl1;
        p += __shfl_xor(p, 16);      // q pairs (0,1) and (2,3) summed
        if ((q & 1) == 0) psum_lds[0][(2*w + (q >> 1))*16 + c] = p;
    }
    __syncthreads();
    if (IS_DEC && t < 16){
        float s32 = 0.f;
        #pragma unroll
        for (int j = 0; j < 32; ++j) s32 += psum_lds[0][j*16 + t];
        u0_lds[t] = s32 + bl_sh;
    }
    __syncthreads();

    for (int s = 0; s < TT; ++s){
        const int cur = s & 1;
        // rotated output flush of previous step (dec): one wave per step
        if (IS_DEC && s > 0 && w == (s & 15) && lane < 16){
            float s32 = 0.f;
            #pragma unroll
            for (int j = 0; j < 32; ++j) s32 += psum_lds[cur ^ 1][j*16 + lane];
            out_lds[lane][TT - s] = s32 + bl_sh;
        }

        float u;
        if (IS_DEC) u = (s == 0) ? u0_lds[c] : x_lds[(TT - s)*16 + c];
        else        u = x_lds[s*16 + c];

        // K-ext B-frag: col c, k=0 -> 1.0, k=1 -> u  (q==0 lanes only)
        bf16x8 b4 = {0,0,0,0,0,0,0,0};
        if (q == 0){ b4[0] = (short)0x3F80; b4[1] = (short)bf16_(u); }

        // K-ext MFMAs first: no LDS dependence, overlap the h ds_read latency
        f32x4 acc0 = {0,0,0,0}, acc1 = {0,0,0,0};
        acc0 = __builtin_amdgcn_mfma_f32_16x16x32_bf16(a40, b4, acc0, 0,0,0);
        acc1 = __builtin_amdgcn_mfma_f32_16x16x32_bf16(a41, b4, acc1, 0,0,0);

        const unsigned short* hb = &h_lds[cur][c*EE];
        {
            bf16x8 bf0 = *(const bf16x8*)&hb[(((0 + q) ^ c) << 3)];
            acc0 = __builtin_amdgcn_mfma_f32_16x16x32_bf16(a00, bf0, acc0, 0,0,0);
            acc1 = __builtin_amdgcn_mfma_f32_16x16x32_bf16(a10, bf0, acc1, 0,0,0);
            bf16x8 bf1 = *(const bf16x8*)&hb[(((4 + q) ^ c) << 3)];
            acc0 = __builtin_amdgcn_mfma_f32_16x16x32_bf16(a01, bf1, acc0, 0,0,0);
            acc1 = __builtin_amdgcn_mfma_f32_16x16x32_bf16(a11, bf1, acc1, 0,0,0);
            bf16x8 bf2 = *(const bf16x8*)&hb[(((8 + q) ^ c) << 3)];
            acc0 = __builtin_amdgcn_mfma_f32_16x16x32_bf16(a02, bf2, acc0, 0,0,0);
            acc1 = __builtin_amdgcn_mfma_f32_16x16x32_bf16(a12, bf2, acc1, 0,0,0);
            bf16x8 bf3 = *(const bf16x8*)&hb[(((12 + q) ^ c) << 3)];
            acc0 = __builtin_amdgcn_mfma_f32_16x16x32_bf16(a03, bf3, acc0, 0,0,0);
            acc1 = __builtin_amdgcn_mfma_f32_16x16x32_bf16(a13, bf3, acc1, 0,0,0);
        }

        // element e0: all four gates lane-local (bias+u*wi already in acc)
        float i0 = sig_  (acc0[0]);
        float f0 = sig_  (acc0[1]);
        float g0 = tanh2_(acc0[2]);
        float o0 = sig_  (acc0[3]);
        cst0 = fmaf(f0, cst0, i0*g0);
        float h0 = o0 * tanh2_(cst0);
        // element e1
        float i1 = sig_  (acc1[0]);
        float f1 = sig_  (acc1[1]);
        float g1 = tanh2_(acc1[2]);
        float o1 = sig_  (acc1[3]);
        cst1 = fmaf(f1, cst1, i1*g1);
        float h1 = o1 * tanh2_(cst1);

        // packed h write: one cvt_pk + one ds_write_b32 (2-way banks = free)
        unsigned hp;
        asm("v_cvt_pk_bf16_f32 %0, %1, %2" : "=v"(hp) : "v"(h0), "v"(h1));
        *(unsigned*)&h_lds[cur ^ 1][c*EE + ((w ^ c) << 3) + 2*q] = hp;

        if (IS_DEC){
            float p = h0*wl0 + h1*wl1;
            p += __shfl_xor(p, 16);
            if ((q & 1) == 0) psum_lds[cur][(2*w + (q >> 1))*16 + c] = p;
        }
        if (!IS_DEC && s == TT-1){
            *(float2*)&ws_h[gb*EE + e0] = make_float2(h0, h1);
            *(float2*)&ws_c[gb*EE + e0] = make_float2(cst0, cst1);
        }
        __syncthreads();
    }

    if (IS_DEC){
        if (w == 0 && lane < 16){   // flush last step (s=TT-1 -> position 0)
            float s32 = 0.f;
            #pragma unroll
            for (int j = 0; j < 32; ++j) s32 += psum_lds[(TT-1)&1][j*16 + lane];
            out_lds[lane][0] = s32 + bl_sh;
        }
        __syncthreads();
        for (int j = t; j < 16*TT; j += 1024){
            int sl = j >> 8, pos = j & 255;
            if (sl < nslots) out[blist[sl]*TT + pos] = out_lds[sl][pos];
        }
    }
}

extern "C" void kernel_launch(void* const* d_in, const int* in_sizes, int n_in,
                              void* d_out, int out_size, void* d_ws, size_t ws_size,
                              hipStream_t stream) {
    const float* x       = (const float*)d_in[0];
    const float* enc_wih = (const float*)d_in[1];
    const float* enc_whh = (const float*)d_in[2];
    const float* enc_b   = (const float*)d_in[3];
    const float* dec_wih = (const float*)d_in[4];
    const float* dec_whh = (const float*)d_in[5];
    const float* dec_b   = (const float*)d_in[6];
    const float* lin_w   = (const float*)d_in[7];
    const float* lin_b   = (const float*)d_in[8];
    float* out  = (float*)d_out;
    float* wsf  = (float*)d_ws;
    float* ws_h = wsf;
    float* ws_c = wsf + BB*EE;   // 512 KB total

    hipLaunchKernelGGL((lstm_k<0>), dim3(BB/16), dim3(1024), 0, stream,
                       x, enc_whh, enc_wih, enc_b, lin_w, lin_b, ws_h, ws_c, out);
    hipLaunchKernelGGL((lstm_k<1>), dim3(16*NCHUNK), dim3(1024), 0, stream,
                       x, dec_whh, dec_wih, dec_b, lin_w, lin_b, ws_h, ws_c, out);
}

// Round 13
// 456.699 us; speedup vs baseline: 2.1374x; 1.7314x over previous
//
#include <hip/hip_runtime.h>
#include <math.h>

#define BB 512   // batch
#define TT 256   // time steps
#define EE 128   // hidden
#define GG 512   // 4*E gate rows
#define XROW 257 // T+1
#define NCHUNK 5 // decoder chunks per id
#define LOG2E 1.44269504088896f

typedef __attribute__((ext_vector_type(8))) short bf16x8;
typedef __attribute__((ext_vector_type(4))) float f32x4;

__device__ __forceinline__ unsigned short bf16_(float f){  // RNE f32->bf16
    unsigned u = __float_as_uint(f);
    return (unsigned short)((u + 0x7fffu + ((u>>16)&1u)) >> 16);
}

// Nonlinearities on PRE-SCALED inputs (a = x*log2e): 2 TRANS + ~2 VALU each.
__device__ __forceinline__ float sig_pre(float a){   // sigmoid(x)
    float e; asm("v_exp_f32 %0, -%1" : "=v"(e) : "v"(a));
    float r; asm("v_rcp_f32 %0, %1" : "=v"(r) : "v"(e + 1.0f));
    return r;
}
__device__ __forceinline__ float tanh_pre(float a){  // tanh(x)
    float a2 = a + a;
    float e; asm("v_exp_f32 %0, -%1" : "=v"(e) : "v"(a2));
    float r; asm("v_rcp_f32 %0, %1" : "=v"(r) : "v"(e + 1.0f));
    return fmaf(2.0f, r, -1.0f);
}
__device__ __forceinline__ float tanh_raw(float x){  // unscaled input
    float m = x * (-2.0f * LOG2E);
    float e; asm("v_exp_f32 %0, %1" : "=v"(e) : "v"(m));
    float r; asm("v_rcp_f32 %0, %1" : "=v"(r) : "v"(e + 1.0f));
    return fmaf(2.0f, r, -1.0f);
}

// Adjacent-element gate-interleaved permutation: tile P of wave w, tile-row
// rho in [0,16): source gate row = (rho&3)*128 + 8w + 2*(rho>>2) + P.
// => C/D lane (q,c): acc_P regs 0..3 = gates (i,f,g,o) of element 8w+2q+P.
__device__ __forceinline__ int perm_row(int P, int w, int rho){
    return (rho & 3)*EE + 8*w + 2*(rho >> 2) + P;
}
// A-frag load with pre-scale (weights multiplied by log2e before bf16 round)
__device__ __forceinline__ bf16x8 load_afrag(const float* W, int row, int k0){
    const float4* p = (const float4*)(W + row*EE + k0);
    float4 a = p[0], b = p[1];
    bf16x8 r;
    r[0]=(short)bf16_(a.x*LOG2E); r[1]=(short)bf16_(a.y*LOG2E);
    r[2]=(short)bf16_(a.z*LOG2E); r[3]=(short)bf16_(a.w*LOG2E);
    r[4]=(short)bf16_(b.x*LOG2E); r[5]=(short)bf16_(b.y*LOG2E);
    r[6]=(short)bf16_(b.z*LOG2E); r[7]=(short)bf16_(b.w*LOG2E);
    return r;
}

template <int IS_DEC>
__global__ __attribute__((amdgpu_flat_work_group_size(1024,1024)))
void lstm_k(const float* __restrict__ x,
            const float* __restrict__ Wg_all,
            const float* __restrict__ wi_all,
            const float* __restrict__ b_all,
            const float* __restrict__ lw_all,
            const float* __restrict__ lb_all,
            float* __restrict__ ws_h,
            float* __restrict__ ws_c,
            float* __restrict__ out)
{
    const int t    = threadIdx.x;   // 1024 threads = 16 waves
    const int w    = t >> 6;        // wave owns e-chunk 8w..8w+7
    const int lane = t & 63;
    const int q    = lane >> 4;
    const int c    = lane & 15;     // batch column (B-frag) / tile-row (A-frag)

    __shared__ unsigned short h_lds[2][16*EE];  // double-buffered bf16 h, swizzled
    __shared__ float x_lds[TT*16];              // inputs [step][col]
    __shared__ float psum_lds[2][512];          // [buf][(2w+qh)*16+c]
    __shared__ float u0_lds[16];
    __shared__ float out_lds[16][TT+1];
    __shared__ int   id_lds[BB];
    __shared__ int   blist[16];
    __shared__ int   nslots_s;
    __shared__ float bl_sh;

    int myid = 0, nslots = 16;
    if (IS_DEC){
        myid = blockIdx.x / NCHUNK;
        int chunk = blockIdx.x % NCHUNK;
        for (int j = t; j < BB; j += 1024) id_lds[j] = (int)x[j*XROW + TT];
        if (t < 16) blist[t] = 0;
        __syncthreads();
        if (t < BB && id_lds[t] == myid){
            int r = 0;
            for (int j = 0; j < t; ++j) r += (id_lds[j] == myid) ? 1 : 0;
            int slot = r - chunk*16;
            if (slot >= 0 && slot < 16) blist[slot] = t;
        }
        if (t == 0){
            int cnt = 0;
            for (int j = 0; j < BB; ++j) cnt += (id_lds[j] == myid) ? 1 : 0;
            int ns = cnt - chunk*16;
            nslots_s = ns < 0 ? 0 : (ns > 16 ? 16 : ns);
            bl_sh = lb_all[myid];
        }
        __syncthreads();
        nslots = nslots_s;
        if (nslots == 0) return;    // uniform exit before loop barriers
    }
    const int gb = IS_DEC ? blist[c] : (blockIdx.x*16 + c);

    for (int j = t; j < TT*16; j += 1024){
        int s = j >> 4, cc = j & 15;
        int gbl = IS_DEC ? blist[cc] : (blockIdx.x*16 + cc);
        x_lds[j] = x[gbl*XROW + s];
    }

    const float* Wb  = Wg_all + (IS_DEC ? myid*GG*EE : 0);
    const float* wib = wi_all + (IS_DEC ? myid*GG : 0);
    const float* bbb = b_all  + (IS_DEC ? myid*GG : 0);

    // weights: 8 main A-frags (32 VGPR) + 2 K-ext frags (8 VGPR), pre-scaled
    bf16x8 a00, a01, a02, a03, a10, a11, a12, a13;
    bf16x8 a40 = {0,0,0,0,0,0,0,0}, a41 = {0,0,0,0,0,0,0,0};
    {
        int kb = 8*q;
        int r0 = perm_row(0, w, c), r1 = perm_row(1, w, c);
        a00 = load_afrag(Wb, r0, kb);      a10 = load_afrag(Wb, r1, kb);
        a01 = load_afrag(Wb, r0, 32+kb);   a11 = load_afrag(Wb, r1, 32+kb);
        a02 = load_afrag(Wb, r0, 64+kb);   a12 = load_afrag(Wb, r1, 64+kb);
        a03 = load_afrag(Wb, r0, 96+kb);   a13 = load_afrag(Wb, r1, 96+kb);
        if (q == 0){   // K-ext tile: k=0 -> bias, k=1 -> wi (both pre-scaled)
            a40[0] = (short)bf16_(bbb[r0]*LOG2E); a40[1] = (short)bf16_(wib[r0]*LOG2E);
            a41[0] = (short)bf16_(bbb[r1]*LOG2E); a41[1] = (short)bf16_(wib[r1]*LOG2E);
        }
    }

    const int e0 = 8*w + 2*q;       // lane's two adjacent elements e0, e0+1
    float cst0 = 0.f, cst1 = 0.f;
    float wl0 = 0.f, wl1 = 0.f;

    if (!IS_DEC){
        ((unsigned*)&h_lds[0][0])[t] = 0u;   // zero buf0
    } else {
        float2 hv = *(const float2*)&ws_h[gb*EE + e0];
        float2 cv = *(const float2*)&ws_c[gb*EE + e0];
        cst0 = cv.x; cst1 = cv.y;
        float2 wv = *(const float2*)&lw_all[myid*EE + e0];
        wl0 = wv.x; wl1 = wv.y;
        unsigned hp;
        asm("v_cvt_pk_bf16_f32 %0, %1, %2" : "=v"(hp) : "v"(hv.x), "v"(hv.y));
        *(unsigned*)&h_lds[0][c*EE + ((w ^ c) << 3) + 2*q] = hp;
        float p = hv.x*wl0 + hv.y*wl1;
        p += __shfl_xor(p, 16);      // q pairs (0,1) and (2,3) summed
        if ((q & 1) == 0) psum_lds[0][(2*w + (q >> 1))*16 + c] = p;
    }
    __syncthreads();
    if (IS_DEC && t < 16){
        float s32 = 0.f;
        #pragma unroll
        for (int j = 0; j < 32; ++j) s32 += psum_lds[0][j*16 + t];
        u0_lds[t] = s32 + bl_sh;
    }
    __syncthreads();

    for (int s = 0; s < TT; ++s){
        const int cur = s & 1;
        // rotated output flush of previous step (dec): one wave per step
        if (IS_DEC && s > 0 && w == (s & 15) && lane < 16){
            float s32 = 0.f;
            #pragma unroll
            for (int j = 0; j < 32; ++j) s32 += psum_lds[cur ^ 1][j*16 + lane];
            out_lds[lane][TT - s] = s32 + bl_sh;
        }

        float u;
        if (IS_DEC) u = (s == 0) ? u0_lds[c] : x_lds[(TT - s)*16 + c];
        else        u = x_lds[s*16 + c];

        // K-ext B-frag: col c, k=0 -> 1.0, k=1 -> u  (q==0 lanes only)
        unsigned pk;
        asm("v_cvt_pk_bf16_f32 %0, %1, %2" : "=v"(pk) : "v"(1.0f), "v"(u));
        union { bf16x8 v; unsigned uu[4]; } bu;
        bu.uu[0] = (q == 0) ? pk : 0u;
        bu.uu[1] = 0u; bu.uu[2] = 0u; bu.uu[3] = 0u;

        // K-ext MFMAs first: no LDS dependence, overlap the h ds_read latency
        f32x4 acc0 = {0,0,0,0}, acc1 = {0,0,0,0};
        acc0 = __builtin_amdgcn_mfma_f32_16x16x32_bf16(a40, bu.v, acc0, 0,0,0);
        acc1 = __builtin_amdgcn_mfma_f32_16x16x32_bf16(a41, bu.v, acc1, 0,0,0);

        const unsigned short* hb = &h_lds[cur][c*EE];
        {
            bf16x8 bf0 = *(const bf16x8*)&hb[(((0 + q) ^ c) << 3)];
            acc0 = __builtin_amdgcn_mfma_f32_16x16x32_bf16(a00, bf0, acc0, 0,0,0);
            acc1 = __builtin_amdgcn_mfma_f32_16x16x32_bf16(a10, bf0, acc1, 0,0,0);
            bf16x8 bf1 = *(const bf16x8*)&hb[(((4 + q) ^ c) << 3)];
            acc0 = __builtin_amdgcn_mfma_f32_16x16x32_bf16(a01, bf1, acc0, 0,0,0);
            acc1 = __builtin_amdgcn_mfma_f32_16x16x32_bf16(a11, bf1, acc1, 0,0,0);
            bf16x8 bf2 = *(const bf16x8*)&hb[(((8 + q) ^ c) << 3)];
            acc0 = __builtin_amdgcn_mfma_f32_16x16x32_bf16(a02, bf2, acc0, 0,0,0);
            acc1 = __builtin_amdgcn_mfma_f32_16x16x32_bf16(a12, bf2, acc1, 0,0,0);
            bf16x8 bf3 = *(const bf16x8*)&hb[(((12 + q) ^ c) << 3)];
            acc0 = __builtin_amdgcn_mfma_f32_16x16x32_bf16(a03, bf3, acc0, 0,0,0);
            acc1 = __builtin_amdgcn_mfma_f32_16x16x32_bf16(a13, bf3, acc1, 0,0,0);
        }

        // element e0: gates lane-local, acc pre-scaled by log2e
        float i0 = sig_pre (acc0[0]);
        float f0 = sig_pre (acc0[1]);
        float g0 = tanh_pre(acc0[2]);
        float o0 = sig_pre (acc0[3]);
        cst0 = fmaf(f0, cst0, i0*g0);
        float h0 = o0 * tanh_raw(cst0);
        // element e1
        float i1 = sig_pre (acc1[0]);
        float f1 = sig_pre (acc1[1]);
        float g1 = tanh_pre(acc1[2]);
        float o1 = sig_pre (acc1[3]);
        cst1 = fmaf(f1, cst1, i1*g1);
        float h1 = o1 * tanh_raw(cst1);

        // packed h write: one cvt_pk + one ds_write_b32 (2-way banks = free)
        unsigned hp;
        asm("v_cvt_pk_bf16_f32 %0, %1, %2" : "=v"(hp) : "v"(h0), "v"(h1));
        *(unsigned*)&h_lds[cur ^ 1][c*EE + ((w ^ c) << 3) + 2*q] = hp;

        if (IS_DEC){
            float p = h0*wl0 + h1*wl1;
            p += __shfl_xor(p, 16);
            if ((q & 1) == 0) psum_lds[cur][(2*w + (q >> 1))*16 + c] = p;
        }
        if (!IS_DEC && s == TT-1){
            *(float2*)&ws_h[gb*EE + e0] = make_float2(h0, h1);
            *(float2*)&ws_c[gb*EE + e0] = make_float2(cst0, cst1);
        }
        __syncthreads();
    }

    if (IS_DEC){
        if (w == 0 && lane < 16){   // flush last step (s=TT-1 -> position 0)
            float s32 = 0.f;
            #pragma unroll
            for (int j = 0; j < 32; ++j) s32 += psum_lds[(TT-1)&1][j*16 + lane];
            out_lds[lane][0] = s32 + bl_sh;
        }
        __syncthreads();
        for (int j = t; j < 16*TT; j += 1024){
            int sl = j >> 8, pos = j & 255;
            if (sl < nslots) out[blist[sl]*TT + pos] = out_lds[sl][pos];
        }
    }
}

extern "C" void kernel_launch(void* const* d_in, const int* in_sizes, int n_in,
                              void* d_out, int out_size, void* d_ws, size_t ws_size,
                              hipStream_t stream) {
    const float* x       = (const float*)d_in[0];
    const float* enc_wih = (const float*)d_in[1];
    const float* enc_whh = (const float*)d_in[2];
    const float* enc_b   = (const float*)d_in[3];
    const float* dec_wih = (const float*)d_in[4];
    const float* dec_whh = (const float*)d_in[5];
    const float* dec_b   = (const float*)d_in[6];
    const float* lin_w   = (const float*)d_in[7];
    const float* lin_b   = (const float*)d_in[8];
    float* out  = (float*)d_out;
    float* wsf  = (float*)d_ws;
    float* ws_h = wsf;
    float* ws_c = wsf + BB*EE;   // 512 KB total

    hipLaunchKernelGGL((lstm_k<0>), dim3(BB/16), dim3(1024), 0, stream,
                       x, enc_whh, enc_wih, enc_b, lin_w, lin_b, ws_h, ws_c, out);
    hipLaunchKernelGGL((lstm_k<1>), dim3(16*NCHUNK), dim3(1024), 0, stream,
                       x, dec_whh, dec_wih, dec_b, lin_w, lin_b, ws_h, ws_c, out);
}